// Round 12
// baseline (125.688 us; speedup 1.0000x reference)
//
#include <hip/hip_runtime.h>
#include <math.h>

#define LAYERS  8
#define FEAT    3072
#define NCLASS  10
#define DIM     4096
#define STD     140   // dword stride between rows (128 dwords data + 12 pad; 35 odd -> b128 quads uniform)

typedef float v2f __attribute__((ext_vector_type(2)));
typedef float v4f __attribute__((ext_vector_type(4)));

// prefix-xor (inverse Gray) of 6-bit value; compile-time under unroll. Note: bit5 preserved.
__device__ __forceinline__ int px6c(int r) {
    int u = r ^ (r >> 1); u ^= u >> 2; u ^= u >> 4; return u & 63;
}
__device__ __forceinline__ int gray6(int r) { return (r ^ (r >> 1)) & 63; }
__device__ __forceinline__ float bpermf(int addr, float x) {
    return __int_as_float(__builtin_amdgcn_ds_bpermute(addr, __float_as_int(x)));
}

// ---- SoA state pairing: v[r] = (P_elem, Q_elem). Every butterfly is a pure
//      cross-register pk op: no swaps, no component unpacking, for ALL stages. ----

// plain 6 reg-bit butterflies; stage p uses cl[off-p]/sl[off-p]
__device__ __forceinline__ void bflies(v2f v[64],
                                       const float* __restrict__ cl,
                                       const float* __restrict__ sl, int off) {
#pragma unroll
    for (int p = 0; p < 6; ++p) {
        const float c = cl[off - p], s = sl[off - p];
        const v2f c2 = {c, c}, s2 = {s, s};
#pragma unroll
        for (int r0 = 0; r0 < 64; ++r0) {
            if (r0 & (1 << p)) continue;
            const int r1 = r0 | (1 << p);
            v2f a = v[r0], e = v[r1];
            v[r0] = a * c2 - e * s2;
            v[r1] = a * s2 + e * c2;
        }
    }
}

// A-phase conjugated by deferred GrayA (verified rounds 7/8): new-bit b pairs
// {s, s^(2^{b+1}-1)}, sign from bit (b+1) of s; b=5 sign per-lane (psgn).
__device__ __forceinline__ void bflies_renamed(v2f v[64],
                                               const float* __restrict__ cl,
                                               const float* __restrict__ sl,
                                               float psgn) {
#pragma unroll
    for (int b = 0; b < 5; ++b) {
        const float c = cl[11 - b], s = sl[11 - b];
        const v2f c2 = {c, c};
#pragma unroll
        for (int s0 = 0; s0 < 64; ++s0) {
            if (s0 & (1 << b)) continue;
            const int s1 = s0 ^ ((2 << b) - 1);
            const float sg = (s0 & (2 << b)) ? -s : s;
            const v2f sg2 = {sg, sg};
            v2f a = v[s0], e = v[s1];
            v[s0] = a * c2 - e * sg2;
            v[s1] = a * sg2 + e * c2;
        }
    }
    {
        const float c = cl[6];
        const float snl = psgn * sl[6];
        const v2f c2 = {c, c}, sg2 = {snl, snl};
#pragma unroll
        for (int s0 = 0; s0 < 32; ++s0) {
            const int s1 = 63 - s0;
            v2f a = v[s0], e = v[s1];
            v[s0] = a * c2 - e * sg2;
            v[s1] = a * sg2 + e * c2;
        }
    }
}

__global__ __launch_bounds__(64, 1)
void qnn_kernel(const float* __restrict__ x,
                const float* __restrict__ ang,
                const float* __restrict__ W,
                const float* __restrict__ bias,
                float* __restrict__ out)
{
    __shared__ __attribute__((aligned(16))) float lds[STD * 64];  // 35840 B (4 blocks/CU)
    __shared__ float cst[96], snt[96];

    const int t  = threadIdx.x;         // 0..63, single wave; two states P(.x), Q(.y)
    const int b0 = 2 * blockIdx.x;
    const int b1 = b0 + 1;

    // ---- trig tables; single wave, in-order DS -> no barriers anywhere ----
    {
        float a0 = ang[t];
        cst[t] = cosf(a0);
        snt[t] = sinf(a0);
        if (t < 32) {
            float a1 = ang[64 + t];
            cst[64 + t] = cosf(a1);
            snt[64 + t] = sinf(a1);
        }
    }

    // ---- load both states in B layout: v[u] = (P[64u+t], Q[64u+t]) ----
    v2f v[64];
    {
        const float* xP = x + (size_t)b0 * FEAT;
        const float* xQ = x + (size_t)b1 * FEAT;
#pragma unroll
        for (int u = 0; u < 64; ++u) {
            if (u < FEAT / 64) {
                v2f nv;
                nv.x = xP[64 * u + t];      // coalesced b32
                nv.y = xQ[64 * u + t];
                v[u] = nv;
            } else {
                v[u] = (v2f){0.f, 0.f};
            }
        }
    }

    // ---- ||x||^2 for both lanes-parallel (normalization deferred) ----
    float invP, invQ;
    {
        v2f s2 = {0.f, 0.f};
#pragma unroll
        for (int u = 0; u < 64; ++u) s2 += v[u] * v[u];
        float sP = s2.x, sQ = s2.y;
#pragma unroll
        for (int o = 1; o < 64; o <<= 1) {
            sP += __shfl_xor(sP, o, 64);
            sQ += __shfl_xor(sQ, o, 64);
        }
        invP = 1.0f / sP;
        invQ = 1.0f / sQ;
    }

    // ---- per-lane constants ----
    int px = t ^ (t >> 1); px ^= px >> 2; px ^= px >> 4; px &= 63;  // px6(t)
    const int A0 = 4 * px;                     // bpermute byte addrs (GrayB)
    const int A1 = 4 * (px ^ 63);
    const int u0 = t & 1;
    const float psgn = u0 ? -1.f : 1.f;        // parity sign for renamed b=5
    const int gtl  = gray6(t);
    const int bpA  = 2 * gtl + STD * 32 * u0;  // folded-GrayA store bases (dwords)
    const int bmA  = 2 * gtl - STD * 32 * u0;

    // ---- layer 0 (even, clean): B-phase, transpose B->A, A-phase ----
    {
        bflies(v, cst, snt, 5);                       // qubits 5..0 (reg = hi bits)
        // B->A: scattered b64 col-writes (banks (70u+t)%16 uniform), b128 row-reads
#pragma unroll
        for (int u = 0; u < 64; ++u)
            *(v2f*)(lds + STD * u + 2 * t) = v[u];
#pragma unroll
        for (int j = 0; j < 32; ++j) {
            v4f q = *(const v4f*)(lds + STD * t + 4 * j);
            v[2 * j]     = (v2f){q.x, q.y};
            v[2 * j + 1] = (v2f){q.z, q.w};
        }
        bflies(v, cst, snt, 11);                      // qubits 11..6 (reg = lo bits)
        // GrayA(0) deferred into layer 1
    }

#pragma unroll 1
    for (int p = 0; p < 4; ++p) {
        const float* cO = cst + (2 * p + 1) * 12;     // odd layer 2p+1
        const float* sO = snt + (2 * p + 1) * 12;

        // ---- renamed A-phase, then transpose A->B with GrayA folded ----
        bflies_renamed(v, cO, sO, psgn);
#pragma unroll
        for (int s = 0; s < 64; ++s) {
            const int g = gray6(s);                   // compile-time
            *(v2f*)(lds + ((g & 32) ? bmA : bpA) + STD * g) = v[s];  // b64, uniform banks
        }
#pragma unroll
        for (int j = 0; j < 32; ++j) {
            v4f q = *(const v4f*)(lds + STD * t + 4 * j);            // b128 rows
            v[2 * j]     = (v2f){q.x, q.y};
            v[2 * j + 1] = (v2f){q.z, q.w};
        }
        bflies(v, cO, sO, 5);                         // B-phase qubits 5..0

        if (p == 3) break;                            // layer 7: Gray folds into epilogue

        // ---- GrayB (eager, bpermute), in invariant halves (px6 preserves bit 5) ----
#pragma unroll
        for (int h = 0; h < 2; ++h) {
            v2f n[32];
#pragma unroll
            for (int k = 0; k < 32; ++k) {
                const int r   = 32 * h + k;
                const int src = px6c(r);              // compile-time, same half
                const int ad  = (src & 1) ? A1 : A0;
                n[k].x = bpermf(ad, v[src].x);
                n[k].y = bpermf(ad, v[src].y);
            }
#pragma unroll
            for (int k = 0; k < 32; ++k) v[32 * h + k] = n[k];
        }

        // ---- even layer 2p+2 (clean): B-phase, transpose B->A, A-phase ----
        {
            const float* cN = cst + (2 * p + 2) * 12;
            const float* sN = snt + (2 * p + 2) * 12;
            bflies(v, cN, sN, 5);
#pragma unroll
            for (int u = 0; u < 64; ++u)
                *(v2f*)(lds + STD * u + 2 * t) = v[u];
#pragma unroll
            for (int j = 0; j < 32; ++j) {
                v4f q = *(const v4f*)(lds + STD * t + 4 * j);
                v[2 * j]     = (v2f){q.x, q.y};
                v[2 * j + 1] = (v2f){q.z, q.w};
            }
            bflies(v, cN, sN, 11);
            // GrayA deferred into next odd layer
        }
    }

    // ---- epilogue: q2[g(j)] = (P^2, Q^2) scattered b64 (Gray(7) folded);
    //      j = 64r + t, g(j) = 64*gray6(r) + (gtl ^ 32*(r&1)); dword = 2*g ----
    const int ga = 2 * gtl;
    const int gb = 2 * (gtl ^ 32);
#pragma unroll
    for (int r = 0; r < 64; ++r) {
        const int gofs = 128 * gray6(r);              // compile-time dword offset
        v2f q;
        q.x = v[r].x * v[r].x;
        q.y = v[r].y * v[r].y;
        *(v2f*)(lds + gofs + ((r & 1) ? gb : ga)) = q;   // banks: gtl%16, uniform
    }

    // ---- shared-W dot products: per k, q b128 = elems {e,e+1}x{P,Q}, W b64 ----
    v2f acc2[NCLASS];
#pragma unroll
    for (int c = 0; c < NCLASS; ++c) acc2[c] = (v2f){0.f, 0.f};

#pragma unroll 1
    for (int k = 0; k < 32; ++k) {
        const v4f q4 = *(const v4f*)(lds + 256 * k + 4 * t);   // b128, quads t%8 uniform
        const v2f qa = {q4.x, q4.y};        // (P,Q) at elem e0 = 128k + 2t
        const v2f qb = {q4.z, q4.w};        // elem e0+1
        const float* wp = W + 128 * k + 2 * t;
#pragma unroll
        for (int c = 0; c < NCLASS; ++c) {
            const v2f w2 = *(const v2f*)(wp + c * DIM);        // dwordx2, coalesced, shared P/Q
            acc2[c] += qa * (v2f){w2.x, w2.x};
            acc2[c] += qb * (v2f){w2.y, w2.y};
        }
    }

#pragma unroll
    for (int c = 0; c < NCLASS; ++c) {
        float aP = acc2[c].x, aQ = acc2[c].y;
#pragma unroll
        for (int o = 1; o < 64; o <<= 1) {
            aP += __shfl_xor(aP, o, 64);
            aQ += __shfl_xor(aQ, o, 64);
        }
        if (t == 0) {
            out[b0 * NCLASS + c] = fmaf(aP, invP, bias[c]);
            out[b1 * NCLASS + c] = fmaf(aQ, invQ, bias[c]);
        }
    }
}

extern "C" void kernel_launch(void* const* d_in, const int* in_sizes, int n_in,
                              void* d_out, int out_size, void* d_ws, size_t ws_size,
                              hipStream_t stream) {
    const float* x    = (const float*)d_in[0];
    const float* ang  = (const float*)d_in[1];
    const float* W    = (const float*)d_in[2];
    const float* bias = (const float*)d_in[3];
    float* out = (float*)d_out;
    const int batch = in_sizes[0] / FEAT;   // 2048
    qnn_kernel<<<batch / 2, 64, 0, stream>>>(x, ang, W, bias, out);
}